// Round 5
// baseline (96.676 us; speedup 1.0000x reference)
//
#include <hip/hip_runtime.h>
#include <hip/hip_fp16.h>

// ApproxConv2d via 256x256 LUT (approximate multiplier).
// out[b,o,y,x] = sum_{c,ky,kx} lut[ qx(b,c,y+ky-1,x+kx-1)*256 + qw(o,c,ky,kx) ] + bias[o]
// qx/qw = clip(rint(v*64), -128, 127) + 128; padding -> qx=128 -> lut row 128 = 0.
//
// v5: o-pair b128 rows. T[pair][c][qx] row = 48B = 3 ky x 16B quad:
// [o0:h(t0)|h(t1), h(t2)|0][o1:h(t0)|h(t1), h(t2)|0]. Each thread owns a 4-px
// strip for BOTH o's (8 accs); per (input px,ky) ONE ds_read_b128 feeds up to
// 3 taps x 2 channels = 6 MACs. DS instrs/CU halve vs v4 (the measured bound:
// LDS issue pipe, ~11.6 cyc/instr). Row stride 48B -> b128 starts hit 8
// disjoint 4-bank groups (near-ideal random spread).
// T_c (12KB) staged via global_load_lds width=16, double-buffered; full-image
// plane (34x40B, dbuf) so no halo staging. Grid 256: bid = b*32+pair so all
// batches of a pair land on XCD pair%8 (table L2-resident, 3.1MB/XCD).

#define NT 256

__device__ __forceinline__ int quantize(float v) {
    // clip(rint(v*64), -128, 127) + 128; rintf = round-half-to-even = jnp.round
    int q = (int)rintf(v * 64.0f);
    q = q < -128 ? -128 : q;
    q = q > 127 ? 127 : q;
    return q + 128;
}

__device__ __forceinline__ float flo(unsigned int u) {
    return __half2float(__ushort_as_half((unsigned short)(u & 0xffffu)));
}
__device__ __forceinline__ float fhi(unsigned int u) {
    return __half2float(__ushort_as_half((unsigned short)(u >> 16)));
}

__device__ __forceinline__ void gll16(const void* g, void* l) {
    __builtin_amdgcn_global_load_lds(
        (const __attribute__((address_space(1))) unsigned int*)g,
        (__attribute__((address_space(3))) unsigned int*)l, 16, 0, 0);
}

// -------- build: T[pair][c][qx] 48B rows; 512 blocks (pair x 16-row slice) --
__global__ __launch_bounds__(NT, 2)
void build_T2(const float* __restrict__ w, const float* __restrict__ lut,
              unsigned int* __restrict__ T)
{
    __shared__ float band[16 * 257];        // 16 lut rows, +1 pad
    __shared__ unsigned char qw2[2][576];

    const int tid = threadIdx.x;
    const int pair = blockIdx.x >> 4;       // 0..31
    const int qq = (blockIdx.x & 15) << 4;  // qx slice base (16 rows)

    for (int i = tid; i < 1152; i += NT) {
        int os = i >= 576;
        int idx = i - os * 576;
        qw2[os][idx] = (unsigned char)quantize(w[(pair * 2 + os) * 576 + idx]);
    }
    for (int i = tid; i < 16 * 256; i += NT) {
        int r = i >> 8, c2 = i & 255;
        band[r * 257 + c2] = lut[qq * 256 + i];
    }
    __syncthreads();

    // 64 c x 16 qxl x 3 ky = 3072 uint4 items; consecutive idx -> coalesced
    for (int it = 0; it < 12; ++it) {
        int idx = it * NT + tid;
        int c = idx / 48;
        int rem = idx - c * 48;
        int qxl = rem / 3;
        int ky = rem - qxl * 3;
        const float* brow = band + qxl * 257;
        unsigned int d[4];
        #pragma unroll
        for (int os = 0; os < 2; ++os) {
            const unsigned char* qp = &qw2[os][c * 9 + ky * 3];
            unsigned int h0 = __half_as_ushort(__float2half(brow[qp[0]]));
            unsigned int h1 = __half_as_ushort(__float2half(brow[qp[1]]));
            unsigned int h2 = __half_as_ushort(__float2half(brow[qp[2]]));
            d[os * 2]     = h0 | (h1 << 16);
            d[os * 2 + 1] = h2;
        }
        size_t off = ((size_t)(pair * 64 + c) * 256 + qq + qxl) * 48 + (size_t)ky * 16;
        *(uint4*)((char*)T + off) = make_uint4(d[0], d[1], d[2], d[3]);
    }
}

// -------- main: block = (pair, b); thread = 4-px strip x 2 o's -------------
__global__ __launch_bounds__(NT, 2)
void approx_main(const float* __restrict__ x, const unsigned int* __restrict__ T,
                 const float* __restrict__ bias, float* __restrict__ out)
{
    __shared__ __align__(16) unsigned char Ts[2][12288];  // T_c double buffer
    __shared__ unsigned int plane[2][340];                // 34 rows x 40B qx plane

    const int tid = threadIdx.x;
    const int bid = blockIdx.x;
    const int pair = bid & 31;               // XCD = bid%8 = pair%8
    const int b = bid >> 5;

    const int yl = tid >> 3;                 // output row 0..31
    const int xs = tid & 7;
    const int x0 = xs << 2;                  // strip base col
    const int wid = tid >> 6, lane = tid & 63;

    const char* Tg = (const char*)T + (size_t)pair * 64 * 12288;
    const float* xb = x + (size_t)b * 65536;

    for (int i = tid; i < 680; i += NT) ((unsigned int*)plane)[i] = 0x80808080u;

    // prologue: prefetch c=0
    {
        const char* src = Tg + wid * 3072 + lane * 16;
        unsigned char* dst = &Ts[0][wid * 3072];
        gll16(src, dst);
        gll16(src + 1024, dst + 1024);
        gll16(src + 2048, dst + 2048);
    }
    float4 xv = *(const float4*)(xb + yl * 32 + x0);

    __syncthreads();   // plane init complete (before first interior write)

    float acc00 = 0.f, acc01 = 0.f, acc02 = 0.f, acc03 = 0.f;
    float acc10 = 0.f, acc11 = 0.f, acc12 = 0.f, acc13 = 0.f;

    for (int c = 0; c < 64; ++c) {
        const int cb = c & 1;
        // write-late: plane[cb] interior from prefetched regs
        unsigned char* pbyte = (unsigned char*)plane[cb];
        int q0 = quantize(xv.x), q1 = quantize(xv.y);
        int q2 = quantize(xv.z), q3 = quantize(xv.w);
        int wb = (yl + 1) * 40 + 2 + x0;
        *(unsigned short*)(pbyte + wb)     = (unsigned short)(q0 | (q1 << 8));
        *(unsigned short*)(pbyte + wb + 2) = (unsigned short)(q2 | (q3 << 8));
        __syncthreads();   // drains gll(c -> Ts[cb]); plane[cb] visible

        // issue-early: c+1 prefetch overlaps compute of c
        if (c < 63) {
            const char* src = Tg + (c + 1) * 12288 + wid * 3072 + lane * 16;
            unsigned char* dst = &Ts[cb ^ 1][wid * 3072];
            gll16(src, dst);
            gll16(src + 1024, dst + 1024);
            gll16(src + 2048, dst + 2048);
            xv = *(const float4*)(xb + (c + 1) * 1024 + yl * 32 + x0);
        }

        const unsigned int* pl = plane[cb];
        const char* Tb = (const char*)&Ts[cb][0];
        #pragma unroll
        for (int ky = 0; ky < 3; ++ky) {
            unsigned int u0 = pl[(yl + ky) * 10 + xs];
            unsigned int u1 = pl[(yl + ky) * 10 + xs + 1];
            // e_j = qx of input cols x0-1 .. x0+4 (plane bytes are col+2)
            int e0 = (int)((u0 >> 8) & 255u), e1 = (int)((u0 >> 16) & 255u);
            int e2 = (int)(u0 >> 24),         e3 = (int)(u1 & 255u);
            int e4 = (int)((u1 >> 8) & 255u), e5 = (int)((u1 >> 16) & 255u);
            const int kyo = ky * 16;
            // row e_j, tap kx feeds acc_{j-kx}; quad = [o0 t0|t1][o0 t2][o1 t0|t1][o1 t2]
            uint4 r0 = *(const uint4*)(Tb + e0 * 48 + kyo);
            acc00 += flo(r0.x);
            acc10 += flo(r0.z);
            uint4 r1 = *(const uint4*)(Tb + e1 * 48 + kyo);
            acc01 += flo(r1.x); acc00 += fhi(r1.x);
            acc11 += flo(r1.z); acc10 += fhi(r1.z);
            uint4 r2 = *(const uint4*)(Tb + e2 * 48 + kyo);
            acc02 += flo(r2.x); acc01 += fhi(r2.x); acc00 += flo(r2.y);
            acc12 += flo(r2.z); acc11 += fhi(r2.z); acc10 += flo(r2.w);
            uint4 r3 = *(const uint4*)(Tb + e3 * 48 + kyo);
            acc03 += flo(r3.x); acc02 += fhi(r3.x); acc01 += flo(r3.y);
            acc13 += flo(r3.z); acc12 += fhi(r3.z); acc11 += flo(r3.w);
            uint4 r4 = *(const uint4*)(Tb + e4 * 48 + kyo);
            acc03 += fhi(r4.x); acc02 += flo(r4.y);
            acc13 += fhi(r4.z); acc12 += flo(r4.w);
            uint4 r5 = *(const uint4*)(Tb + e5 * 48 + kyo);
            acc03 += flo(r5.y);
            acc13 += flo(r5.w);
        }
    }

    const int o0 = pair * 2;
    float b0 = bias[o0], b1 = bias[o0 + 1];
    float4 w0, w1;
    w0.x = acc00 + b0; w0.y = acc01 + b0; w0.z = acc02 + b0; w0.w = acc03 + b0;
    w1.x = acc10 + b1; w1.y = acc11 + b1; w1.z = acc12 + b1; w1.w = acc13 + b1;
    *(float4*)(out + ((size_t)b * 64 + o0) * 1024 + yl * 32 + x0) = w0;
    *(float4*)(out + ((size_t)b * 64 + o0 + 1) * 1024 + yl * 32 + x0) = w1;
}

// -------- fallback (proven v1, 98us): used if ws too small ------------------
#define BW1 61
__global__ __launch_bounds__(NT, 2)
void approxconv2d_v1(const float* __restrict__ x,
                     const float* __restrict__ w,
                     const float* __restrict__ bias,
                     const float* __restrict__ lut,
                     float* __restrict__ out)
{
    __shared__ float band[256 * BW1];
    __shared__ unsigned int plane[340];
    __shared__ unsigned char qwrow[576];
    __shared__ int s_min;

    const int tid = threadIdx.x;
    const int bid = blockIdx.x;
    const int b = bid >> 6;
    const int o = bid & 63;

    if (tid == 0) s_min = 255;
    for (int i = tid; i < 340; i += NT) plane[i] = 0x80808080u;
    __syncthreads();

    int lmin = 255;
    for (int i = tid; i < 576; i += NT) {
        int q = quantize(w[o * 576 + i]);
        qwrow[i] = (unsigned char)q;
        lmin = lmin < q ? lmin : q;
    }
    atomicMin(&s_min, lmin);
    __syncthreads();

    int cmin = s_min;
    if (cmin > 256 - BW1) cmin = 256 - BW1;

    for (int i = tid; i < 256 * BW1; i += NT) {
        int qx = i / BW1;
        int cc = i - qx * BW1;
        band[i] = lut[(qx << 8) + cmin + cc];
    }

    const int y  = tid >> 3;
    const int xq = tid & 7;
    const int x0 = xq << 2;

    float acc0 = 0.f, acc1 = 0.f, acc2 = 0.f, acc3 = 0.f;
    const float* xb = x + (size_t)b * 64 * 1024;
    unsigned char* pb = (unsigned char*)plane;

    for (int c = 0; c < 64; ++c) {
        __syncthreads();
        float4 xv = *(const float4*)(xb + c * 1024 + y * 32 + x0);
        int qa = quantize(xv.x), qb = quantize(xv.y);
        int qc = quantize(xv.z), qd = quantize(xv.w);
        int wbase = (y + 1) * 40 + x0 + 1;
        pb[wbase + 0] = (unsigned char)qa;
        pb[wbase + 1] = (unsigned char)qb;
        pb[wbase + 2] = (unsigned char)qc;
        pb[wbase + 3] = (unsigned char)qd;
        __syncthreads();

        const unsigned char* qwp = qwrow + c * 9;
        #pragma unroll
        for (int ky = 0; ky < 3; ++ky) {
            int ro = (y + ky) * 10 + xq;
            unsigned int r0 = plane[ro];
            unsigned int r1 = plane[ro + 1];
            int ee[6];
            ee[0] = (int)(r0 & 255u);
            ee[1] = (int)((r0 >> 8) & 255u);
            ee[2] = (int)((r0 >> 16) & 255u);
            ee[3] = (int)(r0 >> 24);
            ee[4] = (int)(r1 & 255u);
            ee[5] = (int)((r1 >> 8) & 255u);
            int pp[6];
            #pragma unroll
            for (int t = 0; t < 6; ++t) pp[t] = ee[t] * BW1;
            #pragma unroll
            for (int kx = 0; kx < 3; ++kx) {
                int cq = (int)qwp[ky * 3 + kx];
                int cc = cq - cmin;
                if ((unsigned)cc < (unsigned)BW1) {
                    acc0 += band[pp[kx + 0] + cc];
                    acc1 += band[pp[kx + 1] + cc];
                    acc2 += band[pp[kx + 2] + cc];
                    acc3 += band[pp[kx + 3] + cc];
                } else {
                    acc0 += lut[(ee[kx + 0] << 8) + cq];
                    acc1 += lut[(ee[kx + 1] << 8) + cq];
                    acc2 += lut[(ee[kx + 2] << 8) + cq];
                    acc3 += lut[(ee[kx + 3] << 8) + cq];
                }
            }
        }
    }

    float bo = bias[o];
    float4 r;
    r.x = acc0 + bo; r.y = acc1 + bo; r.z = acc2 + bo; r.w = acc3 + bo;
    *(float4*)(out + (size_t)bid * 1024 + y * 32 + x0) = r;
}

extern "C" void kernel_launch(void* const* d_in, const int* in_sizes, int n_in,
                              void* d_out, int out_size, void* d_ws, size_t ws_size,
                              hipStream_t stream) {
    const float* x    = (const float*)d_in[0];
    const float* wgt  = (const float*)d_in[1];
    const float* bias = (const float*)d_in[2];
    const float* lut  = (const float*)d_in[3];
    float* out = (float*)d_out;

    const size_t T_BYTES = (size_t)32 * 64 * 256 * 48;   // 25,165,824
    if (ws_size >= T_BYTES) {
        hipLaunchKernelGGL(build_T2, dim3(512), dim3(NT), 0, stream,
                           wgt, lut, (unsigned int*)d_ws);
        hipLaunchKernelGGL(approx_main, dim3(256), dim3(NT), 0, stream,
                           x, (const unsigned int*)d_ws, bias, out);
    } else {
        hipLaunchKernelGGL(approxconv2d_v1, dim3(512), dim3(NT), 0, stream,
                           x, wgt, bias, lut, out);
    }
}

// Round 6
// 66.659 us; speedup vs baseline: 1.4503x; 1.4503x over previous
//
#include <hip/hip_runtime.h>
#include <hip/hip_fp16.h>

// ApproxConv2d via 256x256 LUT (approximate multiplier).
// out[b,o,y,x] = sum_{c,ky,kx} lut[ qx(b,c,y+ky-1,x+kx-1)*256 + qw(o,c,ky,kx) ] + bias[o]
// qx/qw = clip(rint(v*64), -128, 127) + 128; padding -> qx=128 -> lut row 128 = 0.
//
// v6: v3's proven b64 tap-row inner loop (T[o][c][qx] = 24B fp16 row
// [ky0 t0|t1][ky0 t2][ky1 ...]) at 16 waves/CU. Block = (b, o, image-half),
// grid 1024 -> 4 blocks/CU (27.5KB LDS each). The 256 threads split into two
// 128-thread halves, each owning one channel PARITY (even/odd c) with its own
// qx-plane; per iteration both halves' T rows (12KB contiguous) are staged via
// global_load_lds w=16 and ONE barrier covers 2 channels. Final cross-half
// reduce (2KB, reuses Ts). Rationale: v3's LDS pipe is only ~59% busy; v5
// showed wave starvation costs 36% -> raise occupancy + halve barrier drains
// with identical per-CU DS work.

#define NT 256

__device__ __forceinline__ int quantize(float v) {
    // clip(rint(v*64), -128, 127) + 128; rintf = round-half-to-even = jnp.round
    int q = (int)rintf(v * 64.0f);
    q = q < -128 ? -128 : q;
    q = q > 127 ? 127 : q;
    return q + 128;
}

__device__ __forceinline__ float flo(unsigned int u) {
    return __half2float(__ushort_as_half((unsigned short)(u & 0xffffu)));
}
__device__ __forceinline__ float fhi(unsigned int u) {
    return __half2float(__ushort_as_half((unsigned short)(u >> 16)));
}

__device__ __forceinline__ void gll16(const void* g, void* l) {
    __builtin_amdgcn_global_load_lds(
        (const __attribute__((address_space(1))) unsigned int*)g,
        (__attribute__((address_space(3))) unsigned int*)l, 16, 0, 0);
}

// -------- build: T[o][c][qx] 24B rows; 1024 blocks = (o, 16-qx-row slice) ---
__global__ __launch_bounds__(NT, 2)
void build_T(const float* __restrict__ w, const float* __restrict__ lut,
             unsigned int* __restrict__ T)
{
    __shared__ float band[16 * 257];        // 16 lut rows, +1 pad
    __shared__ unsigned char qwrow[576];

    const int tid = threadIdx.x;
    const int o = blockIdx.x >> 4;          // 0..63
    const int q0 = (blockIdx.x & 15) << 4;  // qx slice base

    for (int i = tid; i < 576; i += NT)
        qwrow[i] = (unsigned char)quantize(w[o * 576 + i]);
    for (int i = tid; i < 16 * 256; i += NT) {
        int r = i >> 8, c2 = i & 255;
        band[r * 257 + c2] = lut[(q0 + r) * 256 + c2];
    }
    __syncthreads();

    // 64 c x 16 qxl x 3 ky = 3072 uint2 items; ky fastest -> contiguous stores
    for (int it = 0; it < 12; ++it) {
        int idx = it * NT + tid;
        int c = idx / 48;
        int rem = idx - c * 48;
        int qxl = rem / 3;
        int ky = rem - qxl * 3;
        const float* brow = band + qxl * 257;
        const unsigned char* qp = qwrow + c * 9 + ky * 3;
        unsigned int h0 = __half_as_ushort(__float2half(brow[qp[0]]));
        unsigned int h1 = __half_as_ushort(__float2half(brow[qp[1]]));
        unsigned int h2 = __half_as_ushort(__float2half(brow[qp[2]]));
        size_t off = ((size_t)(o * 64 + c) * 256 + q0 + qxl) * 24 + (size_t)ky * 8;
        *(uint2*)((char*)T + off) = make_uint2(h0 | (h1 << 16), h2);
    }
}

// -------- main: block = (b,o,half); halves own channel parity --------------
__global__ __launch_bounds__(NT, 4)
void approx_main(const float* __restrict__ x, const unsigned int* __restrict__ T,
                 const float* __restrict__ bias, float* __restrict__ out)
{
    __shared__ __align__(16) unsigned char Ts[2][12288];  // [buf][cEven 6K | cOdd 6K]
    __shared__ unsigned int plane[2][2][180];             // [parity][buf] 18rows x 40B

    const int tid = threadIdx.x;
    const int bid = blockIdx.x;
    const int o = bid & 63;                  // XCD = bid%8 = o%8 -> T L2-shared
    const int g = bid >> 6;                  // 0..15
    const int b = g >> 1;
    const int h = g & 1;                     // image half (rows 0-15 / 16-31)

    const int hp = tid >> 7;                 // channel parity this thread serves
    const int lt = tid & 127;
    const int yl = lt >> 3;                  // local row 0..15
    const int xs = lt & 7;
    const int x0 = xs << 2;                  // 4-px strip base
    const int yg = (h << 4) + yl;
    const int wid = tid >> 6, lane = tid & 63;

    const char* Tg = (const char*)T + (size_t)o * 393216;  // 64c*256*24
    const float* xb = x + (size_t)b * 65536;

    const int halo_g  = h ? 15 : 16;         // real input row staged as halo
    const int halo_pr = h ? 0  : 17;         // plane row it lands in

    // init all plane buffers to q=128 (outer halos persist)
    for (int i = tid; i < 720; i += NT) ((unsigned int*)plane)[i] = 0x80808080u;

    // prologue: stage t=0 T-pair, prefetch c=hp pixels
    {
        const char* src = Tg + wid * 3072 + lane * 16;
        unsigned char* dst = &Ts[0][wid * 3072];
        gll16(src, dst);
        gll16(src + 1024, dst + 1024);
        gll16(src + 2048, dst + 2048);
    }
    float4 xv = *(const float4*)(xb + hp * 1024 + yg * 32 + x0);
    float xh = (lt < 32) ? xb[hp * 1024 + halo_g * 32 + lt] : 0.f;

    __syncthreads();   // plane init complete

    float acc0 = 0.f, acc1 = 0.f, acc2 = 0.f, acc3 = 0.f;

    for (int t = 0; t < 32; ++t) {
        const int buf = t & 1;
        // write-late: this parity's plane (col j at byte j+4; aligned b32)
        unsigned char* pb = (unsigned char*)plane[hp][buf];
        unsigned int pk = (unsigned int)quantize(xv.x) |
                          ((unsigned int)quantize(xv.y) << 8) |
                          ((unsigned int)quantize(xv.z) << 16) |
                          ((unsigned int)quantize(xv.w) << 24);
        *(unsigned int*)(pb + (yl + 1) * 40 + 4 + x0) = pk;
        if (lt < 32) pb[halo_pr * 40 + 4 + lt] = (unsigned char)quantize(xh);
        __syncthreads();   // drains gll(t -> Ts[buf]); planes visible

        // issue-early: t+1 staging overlaps compute of t
        if (t < 31) {
            const char* src = Tg + (t + 1) * 12288 + wid * 3072 + lane * 16;
            unsigned char* dst = &Ts[buf ^ 1][wid * 3072];
            gll16(src, dst);
            gll16(src + 1024, dst + 1024);
            gll16(src + 2048, dst + 2048);
            const int c1 = 2 * (t + 1) + hp;
            xv = *(const float4*)(xb + c1 * 1024 + yg * 32 + x0);
            if (lt < 32) xh = xb[c1 * 1024 + halo_g * 32 + lt];
        }

        // compute channel c = 2t+hp
        const unsigned char* pr = (const unsigned char*)plane[hp][buf];
        const char* Tb = (const char*)&Ts[buf][0] + hp * 6144;
        #pragma unroll
        for (int ky = 0; ky < 3; ++ky) {
            const int rb = (yl + ky) * 40 + x0;
            unsigned int u0 = *(const unsigned int*)(pr + rb);      // cols x0-4..x0-1
            unsigned int u1 = *(const unsigned int*)(pr + rb + 4);  // cols x0..x0+3
            unsigned int u2 = *(const unsigned int*)(pr + rb + 8);  // col x0+4 in byte0
            int m0 = (int)(u0 >> 24);
            int m1 = (int)(u1 & 255u), m2 = (int)((u1 >> 8) & 255u);
            int m3 = (int)((u1 >> 16) & 255u), m4 = (int)(u1 >> 24);
            int m5 = (int)(u2 & 255u);
            const int kyo = ky * 8;
            // row m_j (input col x0-1+j): t0->acc_j, t1->acc_{j-1}, t2->acc_{j-2}
            uint2 v0 = *(const uint2*)(Tb + m0 * 24 + kyo);
            acc0 += flo(v0.x);
            uint2 v1 = *(const uint2*)(Tb + m1 * 24 + kyo);
            acc1 += flo(v1.x); acc0 += fhi(v1.x);
            uint2 v2 = *(const uint2*)(Tb + m2 * 24 + kyo);
            acc2 += flo(v2.x); acc1 += fhi(v2.x); acc0 += flo(v2.y);
            uint2 v3 = *(const uint2*)(Tb + m3 * 24 + kyo);
            acc3 += flo(v3.x); acc2 += fhi(v3.x); acc1 += flo(v3.y);
            uint2 v4 = *(const uint2*)(Tb + m4 * 24 + kyo);
            acc3 += fhi(v4.x); acc2 += flo(v4.y);
            uint2 v5 = *(const uint2*)(Tb + m5 * 24 + kyo);
            acc3 += flo(v5.y);
        }
    }

    // cross-half reduce (odd-parity partials -> even half), then store
    __syncthreads();
    float* red = (float*)&Ts[0][0];
    if (hp) {
        red[lt * 4 + 0] = acc0; red[lt * 4 + 1] = acc1;
        red[lt * 4 + 2] = acc2; red[lt * 4 + 3] = acc3;
    }
    __syncthreads();
    if (!hp) {
        float bo = bias[o];
        float4 r;
        r.x = acc0 + red[lt * 4 + 0] + bo;
        r.y = acc1 + red[lt * 4 + 1] + bo;
        r.z = acc2 + red[lt * 4 + 2] + bo;
        r.w = acc3 + red[lt * 4 + 3] + bo;
        *(float4*)(out + ((size_t)b * 64 + o) * 1024 + yg * 32 + x0) = r;
    }
}

// -------- fallback (proven v1, 98us): used if ws too small ------------------
#define BW1 61
__global__ __launch_bounds__(NT, 2)
void approxconv2d_v1(const float* __restrict__ x,
                     const float* __restrict__ w,
                     const float* __restrict__ bias,
                     const float* __restrict__ lut,
                     float* __restrict__ out)
{
    __shared__ float band[256 * BW1];
    __shared__ unsigned int plane[340];
    __shared__ unsigned char qwrow[576];
    __shared__ int s_min;

    const int tid = threadIdx.x;
    const int bid = blockIdx.x;
    const int b = bid >> 6;
    const int o = bid & 63;

    if (tid == 0) s_min = 255;
    for (int i = tid; i < 340; i += NT) plane[i] = 0x80808080u;
    __syncthreads();

    int lmin = 255;
    for (int i = tid; i < 576; i += NT) {
        int q = quantize(w[o * 576 + i]);
        qwrow[i] = (unsigned char)q;
        lmin = lmin < q ? lmin : q;
    }
    atomicMin(&s_min, lmin);
    __syncthreads();

    int cmin = s_min;
    if (cmin > 256 - BW1) cmin = 256 - BW1;

    for (int i = tid; i < 256 * BW1; i += NT) {
        int qx = i / BW1;
        int cc = i - qx * BW1;
        band[i] = lut[(qx << 8) + cmin + cc];
    }

    const int y  = tid >> 3;
    const int xq = tid & 7;
    const int x0 = xq << 2;

    float acc0 = 0.f, acc1 = 0.f, acc2 = 0.f, acc3 = 0.f;
    const float* xb = x + (size_t)b * 64 * 1024;
    unsigned char* pb = (unsigned char*)plane;

    for (int c = 0; c < 64; ++c) {
        __syncthreads();
        float4 xv = *(const float4*)(xb + c * 1024 + y * 32 + x0);
        int qa = quantize(xv.x), qb = quantize(xv.y);
        int qc = quantize(xv.z), qd = quantize(xv.w);
        int wbase = (y + 1) * 40 + x0 + 1;
        pb[wbase + 0] = (unsigned char)qa;
        pb[wbase + 1] = (unsigned char)qb;
        pb[wbase + 2] = (unsigned char)qc;
        pb[wbase + 3] = (unsigned char)qd;
        __syncthreads();

        const unsigned char* qwp = qwrow + c * 9;
        #pragma unroll
        for (int ky = 0; ky < 3; ++ky) {
            int ro = (y + ky) * 10 + xq;
            unsigned int r0 = plane[ro];
            unsigned int r1 = plane[ro + 1];
            int ee[6];
            ee[0] = (int)(r0 & 255u);
            ee[1] = (int)((r0 >> 8) & 255u);
            ee[2] = (int)((r0 >> 16) & 255u);
            ee[3] = (int)(r0 >> 24);
            ee[4] = (int)(r1 & 255u);
            ee[5] = (int)((r1 >> 8) & 255u);
            int pp[6];
            #pragma unroll
            for (int t = 0; t < 6; ++t) pp[t] = ee[t] * BW1;
            #pragma unroll
            for (int kx = 0; kx < 3; ++kx) {
                int cq = (int)qwp[ky * 3 + kx];
                int cc = cq - cmin;
                if ((unsigned)cc < (unsigned)BW1) {
                    acc0 += band[pp[kx + 0] + cc];
                    acc1 += band[pp[kx + 1] + cc];
                    acc2 += band[pp[kx + 2] + cc];
                    acc3 += band[pp[kx + 3] + cc];
                } else {
                    acc0 += lut[(ee[kx + 0] << 8) + cq];
                    acc1 += lut[(ee[kx + 1] << 8) + cq];
                    acc2 += lut[(ee[kx + 2] << 8) + cq];
                    acc3 += lut[(ee[kx + 3] << 8) + cq];
                }
            }
        }
    }

    float bo = bias[o];
    float4 r;
    r.x = acc0 + bo; r.y = acc1 + bo; r.z = acc2 + bo; r.w = acc3 + bo;
    *(float4*)(out + (size_t)bid * 1024 + y * 32 + x0) = r;
}

extern "C" void kernel_launch(void* const* d_in, const int* in_sizes, int n_in,
                              void* d_out, int out_size, void* d_ws, size_t ws_size,
                              hipStream_t stream) {
    const float* x    = (const float*)d_in[0];
    const float* wgt  = (const float*)d_in[1];
    const float* bias = (const float*)d_in[2];
    const float* lut  = (const float*)d_in[3];
    float* out = (float*)d_out;

    const size_t T_BYTES = (size_t)64 * 64 * 256 * 24;   // 25,165,824
    if (ws_size >= T_BYTES) {
        hipLaunchKernelGGL(build_T, dim3(1024), dim3(NT), 0, stream,
                           wgt, lut, (unsigned int*)d_ws);
        hipLaunchKernelGGL(approx_main, dim3(1024), dim3(NT), 0, stream,
                           x, (const unsigned int*)d_ws, bias, out);
    } else {
        hipLaunchKernelGGL(approxconv2d_v1, dim3(512), dim3(NT), 0, stream,
                           x, wgt, bias, lut, out);
    }
}

// Round 7
// 53.959 us; speedup vs baseline: 1.7916x; 1.2354x over previous
//
#include <hip/hip_runtime.h>
#include <hip/hip_fp16.h>

// ApproxConv2d via 256x256 LUT (approximate multiplier).
// out[b,o,y,x] = sum_{c,ky,kx} lut[ qx(b,c,y+ky-1,x+kx-1)*256 + qw(o,c,ky,kx) ] + bias[o]
// qx/qw = clip(rint(v*64), -128, 127) + 128; padding -> qx=128 -> lut row 128 = 0.
//
// v7: tap-interleaved o-pair rows + packed-fp16 accumulate.
// T[pair][c][ky][qx] = 12B = 3 words w_k = half(o0 tap_k) | half(o1 tap_k)<<16.
// Row fetch = 3x b32 (stride 3 words, gcd(3,32)=1 -> all-bank spread ~4.6cyc);
// 8-px strips: 28 useful b32/ky feed 48 MACs (2.67 B/MAC vs v6's 4 -> LDS pipe
// cycles ~halve). MAC = __hadd2(acc2, w_k): 2 MACs in 1 VALU op, no cvt;
// fp16 partials migrated to f32 every 2 channels (18-term chunks, bounded err).
// Block = (b, pair, half): 4 channel-parities x 64 threads; single-buffer T
// (4ch x 9216B staged per iter via global_load_lds), dbuf qx-planes; 2
// barriers / 4 channels. Grid 512, bid%8 = pair%8 -> per-XCD T slice 2.4MB.

#define NT 256

__device__ __forceinline__ int quantize(float v) {
    // clip(rint(v*64), -128, 127) + 128; rintf = round-half-to-even = jnp.round
    int q = (int)rintf(v * 64.0f);
    q = q < -128 ? -128 : q;
    q = q > 127 ? 127 : q;
    return q + 128;
}

__device__ __forceinline__ void gll16(const void* g, void* l) {
    __builtin_amdgcn_global_load_lds(
        (const __attribute__((address_space(1))) unsigned int*)g,
        (__attribute__((address_space(3))) unsigned int*)l, 16, 0, 0);
}

// -------- build: T[pair][c][ky][qx] 12B tap-interleaved rows ----------------
// 512 blocks = (pair, 16-qx slice). Band in LDS (stride 257, conflict-free).
__global__ __launch_bounds__(NT, 2)
void build_T3(const float* __restrict__ w, const float* __restrict__ lut,
              unsigned int* __restrict__ T)
{
    __shared__ float band[16 * 257];
    __shared__ unsigned char qw2[2][576];

    const int tid = threadIdx.x;
    const int pair = blockIdx.x >> 4;       // 0..31
    const int qq = (blockIdx.x & 15) << 4;  // qx slice base (16 rows)

    for (int i = tid; i < 1152; i += NT) {
        int os = i >= 576;
        int idx = i - os * 576;
        qw2[os][idx] = (unsigned char)quantize(w[(pair * 2 + os) * 576 + idx]);
    }
    for (int i = tid; i < 16 * 256; i += NT) {
        int r = i >> 8, c2 = i & 255;
        band[r * 257 + c2] = lut[(qq + r) * 256 + c2];
    }
    __syncthreads();

    // 64 c x 3 ky x 16 qxl = 3072 items; idx = c*48 + ky*16 + qxl
    for (int it = 0; it < 12; ++it) {
        int idx = it * NT + tid;
        int c = idx / 48;
        int rem = idx - c * 48;
        int ky = rem >> 4;
        int qxl = rem & 15;
        const float* brow = band + qxl * 257;
        const unsigned char* q0 = &qw2[0][c * 9 + ky * 3];
        const unsigned char* q1 = &qw2[1][c * 9 + ky * 3];
        unsigned int wd[3];
        #pragma unroll
        for (int k = 0; k < 3; ++k) {
            unsigned int h0 = __half_as_ushort(__float2half(brow[q0[k]]));
            unsigned int h1 = __half_as_ushort(__float2half(brow[q1[k]]));
            wd[k] = h0 | (h1 << 16);
        }
        unsigned int* dst = T + ((size_t)((pair * 64 + c) * 3 + ky) * 256 + qq + qxl) * 3;
        dst[0] = wd[0]; dst[1] = wd[1]; dst[2] = wd[2];
    }
}

// -------- main: block = (b, pair, half); 4 parities x 64 thr; 8-px strips ---
__global__ __launch_bounds__(NT, 2)
void approx_main(const float* __restrict__ x, const unsigned int* __restrict__ T,
                 const float* __restrict__ bias, float* __restrict__ out)
{
    __shared__ __align__(16) unsigned char Ts[36864];   // 4 channels x 9216B
    __shared__ unsigned int plane[4][2][180];           // [parity][buf] 18r x 40B

    const int tid = threadIdx.x;
    const int bid = blockIdx.x;
    const int pair = bid & 31;               // XCD = bid%8 = pair%8
    const int bh = bid >> 5;                 // 0..15
    const int b = bh >> 1;
    const int h = bh & 1;

    const int parity = tid >> 6;             // channel parity (c mod 4)
    const int lt = tid & 63;
    const int yl = lt >> 2;                  // local out row 0..15
    const int xs = lt & 3;
    const int x0 = xs << 3;                  // 8-px strip base col
    const int yg = (h << 4) + yl;

    const char* Tg = (const char*)T + (size_t)pair * 589824;  // 64*3*256*12
    const float* xb = x + (size_t)b * 65536;

    const int halo_g  = h ? 15 : 16;         // real input row staged as halo
    const int halo_pr = h ? 0  : 17;         // plane row it lands in

    for (int i = tid; i < 1440; i += NT) ((unsigned int*)plane)[i] = 0x80808080u;

    // prologue: prefetch c = parity pixels
    float4 xv0 = *(const float4*)(xb + parity * 1024 + yg * 32 + x0);
    float4 xv1 = *(const float4*)(xb + parity * 1024 + yg * 32 + x0 + 4);
    float xh = (lt < 32) ? xb[parity * 1024 + halo_g * 32 + lt] : 0.f;

    __syncthreads();   // plane init complete

    const __half2 z2 = __float2half2_rn(0.f);
    float a32[8], b32[8];
    __half2 acc2[8];
    #pragma unroll
    for (int k = 0; k < 8; ++k) { a32[k] = 0.f; b32[k] = 0.f; acc2[k] = z2; }

    for (int t = 0; t < 16; ++t) {
        const int buf = t & 1;
        // plane write (this parity's channel c = 4t+parity)
        unsigned char* pb = (unsigned char*)plane[parity][buf];
        unsigned int pk0 = (unsigned int)quantize(xv0.x) |
                           ((unsigned int)quantize(xv0.y) << 8) |
                           ((unsigned int)quantize(xv0.z) << 16) |
                           ((unsigned int)quantize(xv0.w) << 24);
        unsigned int pk1 = (unsigned int)quantize(xv1.x) |
                           ((unsigned int)quantize(xv1.y) << 8) |
                           ((unsigned int)quantize(xv1.z) << 16) |
                           ((unsigned int)quantize(xv1.w) << 24);
        *(unsigned int*)(pb + (yl + 1) * 40 + 4 + x0)     = pk0;
        *(unsigned int*)(pb + (yl + 1) * 40 + 4 + x0 + 4) = pk1;
        if (lt < 32) pb[halo_pr * 40 + 4 + lt] = (unsigned char)quantize(xh);

        // stage 4 channels' T (36864B) for this t
        {
            const char* src = Tg + t * 36864 + tid * 16;
            char* dst = (char*)Ts + tid * 16;
            #pragma unroll
            for (int k = 0; k < 9; ++k) gll16(src + k * 4096, dst + k * 4096);
        }
        // prefetch next channel's pixels
        if (t < 15) {
            const int c1 = 4 * (t + 1) + parity;
            xv0 = *(const float4*)(xb + c1 * 1024 + yg * 32 + x0);
            xv1 = *(const float4*)(xb + c1 * 1024 + yg * 32 + x0 + 4);
            if (lt < 32) xh = xb[c1 * 1024 + halo_g * 32 + lt];
        }
        __syncthreads();   // gll drained; planes visible

        // compute channel c = 4t+parity
        const unsigned int* pl = plane[parity][buf];
        const char* Tc = (const char*)Ts + parity * 9216;
        #pragma unroll
        for (int ky = 0; ky < 3; ++ky) {
            const int prow = (yl + ky) * 10 + (x0 >> 2);
            uint2 ua = *(const uint2*)&pl[prow];       // cols x0-4..x0-1 | x0..x0+3
            uint2 ub = *(const uint2*)&pl[prow + 2];   // cols x0+4..x0+7 | x0+8..
            int m[10];
            m[0] = (int)(ua.x >> 24);
            m[1] = (int)(ua.y & 255u);  m[2] = (int)((ua.y >> 8) & 255u);
            m[3] = (int)((ua.y >> 16) & 255u); m[4] = (int)(ua.y >> 24);
            m[5] = (int)(ub.x & 255u);  m[6] = (int)((ub.x >> 8) & 255u);
            m[7] = (int)((ub.x >> 16) & 255u); m[8] = (int)(ub.x >> 24);
            m[9] = (int)(ub.y & 255u);
            const char* Tk = Tc + ky * 3072;
            #pragma unroll
            for (int j = 0; j < 10; ++j) {
                const unsigned int* R = (const unsigned int*)(Tk + m[j] * 12);
                // w_k = half(o0 tap_k) | half(o1 tap_k)<<16; tap kx feeds px j-kx
                if (j <= 7) {
                    unsigned int w0 = R[0];
                    acc2[j] = __hadd2(acc2[j], *(const __half2*)&w0);
                }
                if (j >= 1 && j <= 8) {
                    unsigned int w1 = R[1];
                    acc2[j - 1] = __hadd2(acc2[j - 1], *(const __half2*)&w1);
                }
                if (j >= 2) {
                    unsigned int w2 = R[2];
                    acc2[j - 2] = __hadd2(acc2[j - 2], *(const __half2*)&w2);
                }
            }
        }
        // migrate fp16 partials to f32 every 2 channels (bounded rounding)
        if (t & 1) {
            #pragma unroll
            for (int k = 0; k < 8; ++k) {
                a32[k] += __low2float(acc2[k]);
                b32[k] += __high2float(acc2[k]);
                acc2[k] = z2;
            }
        }
        __syncthreads();   // compute done before next stage overwrites Ts
    }

    // cross-parity reduce: parities 1..3 dump, parity 0 sums + bias + store
    float* red = (float*)Ts;
    if (parity) {
        #pragma unroll
        for (int k = 0; k < 8; ++k) {
            red[(parity - 1) * 1024 + lt * 16 + k]     = a32[k];
            red[(parity - 1) * 1024 + lt * 16 + 8 + k] = b32[k];
        }
    }
    __syncthreads();
    if (!parity) {
        const int o0 = pair * 2;
        float bo0 = bias[o0], bo1 = bias[o0 + 1];
        float r0[8], r1[8];
        #pragma unroll
        for (int k = 0; k < 8; ++k) {
            r0[k] = a32[k] + red[lt * 16 + k] + red[1024 + lt * 16 + k]
                  + red[2048 + lt * 16 + k] + bo0;
            r1[k] = b32[k] + red[lt * 16 + 8 + k] + red[1024 + lt * 16 + 8 + k]
                  + red[2048 + lt * 16 + 8 + k] + bo1;
        }
        float* p0 = out + ((size_t)b * 64 + o0) * 1024 + yg * 32 + x0;
        *(float4*)(p0)     = make_float4(r0[0], r0[1], r0[2], r0[3]);
        *(float4*)(p0 + 4) = make_float4(r0[4], r0[5], r0[6], r0[7]);
        float* p1 = p0 + 1024;
        *(float4*)(p1)     = make_float4(r1[0], r1[1], r1[2], r1[3]);
        *(float4*)(p1 + 4) = make_float4(r1[4], r1[5], r1[6], r1[7]);
    }
}

// -------- fallback (proven v1, 98us): used if ws too small ------------------
#define BW1 61
__global__ __launch_bounds__(NT, 2)
void approxconv2d_v1(const float* __restrict__ x,
                     const float* __restrict__ w,
                     const float* __restrict__ bias,
                     const float* __restrict__ lut,
                     float* __restrict__ out)
{
    __shared__ float band[256 * BW1];
    __shared__ unsigned int plane[340];
    __shared__ unsigned char qwrow[576];
    __shared__ int s_min;

    const int tid = threadIdx.x;
    const int bid = blockIdx.x;
    const int b = bid >> 6;
    const int o = bid & 63;

    if (tid == 0) s_min = 255;
    for (int i = tid; i < 340; i += NT) plane[i] = 0x80808080u;
    __syncthreads();

    int lmin = 255;
    for (int i = tid; i < 576; i += NT) {
        int q = quantize(w[o * 576 + i]);
        qwrow[i] = (unsigned char)q;
        lmin = lmin < q ? lmin : q;
    }
    atomicMin(&s_min, lmin);
    __syncthreads();

    int cmin = s_min;
    if (cmin > 256 - BW1) cmin = 256 - BW1;

    for (int i = tid; i < 256 * BW1; i += NT) {
        int qx = i / BW1;
        int cc = i - qx * BW1;
        band[i] = lut[(qx << 8) + cmin + cc];
    }

    const int y  = tid >> 3;
    const int xq = tid & 7;
    const int x0 = xq << 2;

    float acc0 = 0.f, acc1 = 0.f, acc2 = 0.f, acc3 = 0.f;
    const float* xb = x + (size_t)b * 64 * 1024;
    unsigned char* pb = (unsigned char*)plane;

    for (int c = 0; c < 64; ++c) {
        __syncthreads();
        float4 xv = *(const float4*)(xb + c * 1024 + y * 32 + x0);
        int qa = quantize(xv.x), qb = quantize(xv.y);
        int qc = quantize(xv.z), qd = quantize(xv.w);
        int wbase = (y + 1) * 40 + x0 + 1;
        pb[wbase + 0] = (unsigned char)qa;
        pb[wbase + 1] = (unsigned char)qb;
        pb[wbase + 2] = (unsigned char)qc;
        pb[wbase + 3] = (unsigned char)qd;
        __syncthreads();

        const unsigned char* qwp = qwrow + c * 9;
        #pragma unroll
        for (int ky = 0; ky < 3; ++ky) {
            int ro = (y + ky) * 10 + xq;
            unsigned int r0 = plane[ro];
            unsigned int r1 = plane[ro + 1];
            int ee[6];
            ee[0] = (int)(r0 & 255u);
            ee[1] = (int)((r0 >> 8) & 255u);
            ee[2] = (int)((r0 >> 16) & 255u);
            ee[3] = (int)(r0 >> 24);
            ee[4] = (int)(r1 & 255u);
            ee[5] = (int)((r1 >> 8) & 255u);
            int pp[6];
            #pragma unroll
            for (int tt = 0; tt < 6; ++tt) pp[tt] = ee[tt] * BW1;
            #pragma unroll
            for (int kx = 0; kx < 3; ++kx) {
                int cq = (int)qwp[ky * 3 + kx];
                int cc = cq - cmin;
                if ((unsigned)cc < (unsigned)BW1) {
                    acc0 += band[pp[kx + 0] + cc];
                    acc1 += band[pp[kx + 1] + cc];
                    acc2 += band[pp[kx + 2] + cc];
                    acc3 += band[pp[kx + 3] + cc];
                } else {
                    acc0 += lut[(ee[kx + 0] << 8) + cq];
                    acc1 += lut[(ee[kx + 1] << 8) + cq];
                    acc2 += lut[(ee[kx + 2] << 8) + cq];
                    acc3 += lut[(ee[kx + 3] << 8) + cq];
                }
            }
        }
    }

    float bo = bias[o];
    float4 r;
    r.x = acc0 + bo; r.y = acc1 + bo; r.z = acc2 + bo; r.w = acc3 + bo;
    *(float4*)(out + (size_t)bid * 1024 + y * 32 + x0) = r;
}

extern "C" void kernel_launch(void* const* d_in, const int* in_sizes, int n_in,
                              void* d_out, int out_size, void* d_ws, size_t ws_size,
                              hipStream_t stream) {
    const float* x    = (const float*)d_in[0];
    const float* wgt  = (const float*)d_in[1];
    const float* bias = (const float*)d_in[2];
    const float* lut  = (const float*)d_in[3];
    float* out = (float*)d_out;

    const size_t T_BYTES = (size_t)32 * 64 * 3 * 256 * 12;   // 18,874,368
    if (ws_size >= T_BYTES) {
        hipLaunchKernelGGL(build_T3, dim3(512), dim3(NT), 0, stream,
                           wgt, lut, (unsigned int*)d_ws);
        hipLaunchKernelGGL(approx_main, dim3(512), dim3(NT), 0, stream,
                           x, (const unsigned int*)d_ws, bias, out);
    } else {
        hipLaunchKernelGGL(approxconv2d_v1, dim3(512), dim3(NT), 0, stream,
                           x, wgt, bias, lut, out);
    }
}